// Round 1
// baseline (182.740 us; speedup 1.0000x reference)
//
#include <hip/hip_runtime.h>
#include <hip/hip_bf16.h>

#define N_NODES 100000
#define N_EDGES 1600000
#define IN_F 256
#define OUT_F 128

// ---------- helpers ----------
__device__ __forceinline__ float bf16_lo(unsigned int p) {
    union { unsigned int i; float f; } u; u.i = p << 16; return u.f;
}
__device__ __forceinline__ float bf16_hi(unsigned int p) {
    union { unsigned int i; float f; } u; u.i = p & 0xffff0000u; return u.f;
}
__device__ __forceinline__ unsigned short f2bf(float f) {
    union { float f; unsigned int i; } u; u.f = f;
    unsigned int r = u.i + 0x7fff + ((u.i >> 16) & 1);   // RNE (finite data only)
    return (unsigned short)(r >> 16);
}

// ---------- kernel 1: support = X @ W, stored as packed bf16 ----------
// block = 256 threads, computes 64 rows x 128 cols. K tiled by 32.
// LDS: Wt 16 KB + Xt (padded) ~8.3 KB.
__global__ __launch_bounds__(256) void gemm_xw_kernel(
    const float* __restrict__ x, const float* __restrict__ weight,
    unsigned int* __restrict__ support /* N_NODES x 64 uints (2 bf16 each) */) {
  __shared__ float Wt[32][128];
  __shared__ float Xt[64][33];
  const int tid  = threadIdx.x;
  const int row0 = blockIdx.x * 64;
  const int tcol = tid & 15;   // 16 col-groups x 8 cols
  const int trow = tid >> 4;   // 16 row-groups x 4 rows

  float acc[4][8];
  #pragma unroll
  for (int j = 0; j < 4; ++j)
    #pragma unroll
    for (int c = 0; c < 8; ++c) acc[j][c] = 0.f;

  for (int k0 = 0; k0 < IN_F; k0 += 32) {
    // stage W tile: 32x128 floats = 1024 float4, 4 per thread
    #pragma unroll
    for (int i = 0; i < 4; ++i) {
      int fl = tid + i * 256;           // 0..1023
      int kk = fl >> 5;                 // 32 float4 per k-row
      int c4 = (fl & 31) * 4;
      float4 v = *(const float4*)(weight + (size_t)(k0 + kk) * OUT_F + c4);
      *(float4*)(&Wt[kk][c4]) = v;
    }
    // stage X tile: 64x32 floats = 512 float4, 2 per thread
    #pragma unroll
    for (int i = 0; i < 2; ++i) {
      int fl = tid + i * 256;           // 0..511
      int r  = fl >> 3;                 // 8 float4 per row
      int c4 = (fl & 7) * 4;
      int row = row0 + r;
      float4 v = make_float4(0.f, 0.f, 0.f, 0.f);
      if (row < N_NODES) v = *(const float4*)(x + (size_t)row * IN_F + k0 + c4);
      Xt[r][c4 + 0] = v.x; Xt[r][c4 + 1] = v.y;
      Xt[r][c4 + 2] = v.z; Xt[r][c4 + 3] = v.w;
    }
    __syncthreads();
    #pragma unroll
    for (int kk = 0; kk < 32; ++kk) {
      float4 w0 = *(const float4*)(&Wt[kk][tcol * 8]);
      float4 w1 = *(const float4*)(&Wt[kk][tcol * 8 + 4]);
      #pragma unroll
      for (int j = 0; j < 4; ++j) {
        float xv = Xt[trow * 4 + j][kk];
        acc[j][0] += xv * w0.x; acc[j][1] += xv * w0.y;
        acc[j][2] += xv * w0.z; acc[j][3] += xv * w0.w;
        acc[j][4] += xv * w1.x; acc[j][5] += xv * w1.y;
        acc[j][6] += xv * w1.z; acc[j][7] += xv * w1.w;
      }
    }
    __syncthreads();
  }
  // store 8 bf16 (16 B) per thread per row
  #pragma unroll
  for (int j = 0; j < 4; ++j) {
    int row = row0 + trow * 4 + j;
    if (row >= N_NODES) continue;
    union { unsigned short h[8]; uint4 v; } pack;
    #pragma unroll
    for (int c = 0; c < 8; ++c) pack.h[c] = f2bf(acc[j][c]);
    *(uint4*)((unsigned short*)support + (size_t)row * OUT_F + tcol * 8) = pack.v;
  }
}

// ---------- kernel 2: row_ptr via binary search (edge_row is sorted) ----------
__global__ __launch_bounds__(256) void rowptr_kernel(
    const int* __restrict__ edge_row, int* __restrict__ row_ptr) {
  int r = blockIdx.x * 256 + threadIdx.x;
  if (r > N_NODES) return;
  int lo = 0, hi = N_EDGES;
  while (lo < hi) {
    int mid = (lo + hi) >> 1;
    if (edge_row[mid] < r) lo = mid + 1; else hi = mid;
  }
  row_ptr[r] = lo;  // first edge with row >= r
}

// ---------- kernel 3: CSR SpMM, one wave per output row, no atomics ----------
__global__ __launch_bounds__(256) void spmm_kernel(
    const unsigned int* __restrict__ support,  // 64 uints / row (2 bf16 each)
    const int* __restrict__ row_ptr,
    const int* __restrict__ edge_col,
    const float* __restrict__ edge_val,
    const float* __restrict__ bias,
    float* __restrict__ out) {
  int wid = (blockIdx.x * 256 + threadIdx.x) >> 6;   // row id
  if (wid >= N_NODES) return;
  int lane  = threadIdx.x & 63;
  int start = row_ptr[wid];
  int end   = row_ptr[wid + 1];
  float acc0 = 0.f, acc1 = 0.f;

  int e = start;
  for (; e + 4 <= end; e += 4) {
    int   c0 = edge_col[e + 0], c1 = edge_col[e + 1];
    int   c2 = edge_col[e + 2], c3 = edge_col[e + 3];
    float v0 = edge_val[e + 0], v1 = edge_val[e + 1];
    float v2 = edge_val[e + 2], v3 = edge_val[e + 3];
    unsigned int s0 = support[(size_t)c0 * 64 + lane];
    unsigned int s1 = support[(size_t)c1 * 64 + lane];
    unsigned int s2 = support[(size_t)c2 * 64 + lane];
    unsigned int s3 = support[(size_t)c3 * 64 + lane];
    acc0 += v0 * bf16_lo(s0); acc1 += v0 * bf16_hi(s0);
    acc0 += v1 * bf16_lo(s1); acc1 += v1 * bf16_hi(s1);
    acc0 += v2 * bf16_lo(s2); acc1 += v2 * bf16_hi(s2);
    acc0 += v3 * bf16_lo(s3); acc1 += v3 * bf16_hi(s3);
  }
  for (; e < end; ++e) {
    int   c = edge_col[e];
    float v = edge_val[e];
    unsigned int s = support[(size_t)c * 64 + lane];
    acc0 += v * bf16_lo(s); acc1 += v * bf16_hi(s);
  }
  float2 b = *(const float2*)(bias + lane * 2);
  float2 o; o.x = acc0 + b.x; o.y = acc1 + b.y;
  *(float2*)(out + (size_t)wid * OUT_F + lane * 2) = o;
}

// ---------- launch ----------
extern "C" void kernel_launch(void* const* d_in, const int* in_sizes, int n_in,
                              void* d_out, int out_size, void* d_ws, size_t ws_size,
                              hipStream_t stream) {
  const float* x        = (const float*)d_in[0];
  const int*   edge_row = (const int*)  d_in[1];
  const int*   edge_col = (const int*)  d_in[2];
  const float* edge_val = (const float*)d_in[3];
  const float* weight   = (const float*)d_in[4];
  const float* bias     = (const float*)d_in[5];
  float* out = (float*)d_out;

  unsigned char* ws = (unsigned char*)d_ws;
  size_t support_bytes = (size_t)N_NODES * OUT_F * 2;            // 25.6 MB bf16
  unsigned int* support = (unsigned int*)ws;
  int* row_ptr = (int*)(ws + ((support_bytes + 255) & ~(size_t)255));

  hipLaunchKernelGGL(gemm_xw_kernel, dim3((N_NODES + 63) / 64), dim3(256), 0, stream,
                     x, weight, support);
  hipLaunchKernelGGL(rowptr_kernel, dim3((N_NODES + 1 + 255) / 256), dim3(256), 0, stream,
                     edge_row, row_ptr);
  hipLaunchKernelGGL(spmm_kernel, dim3(N_NODES / 4), dim3(256), 0, stream,
                     support, row_ptr, edge_col, edge_val, bias, out);
}

// Round 2
// 111.212 us; speedup vs baseline: 1.6432x; 1.6432x over previous
//
#include <hip/hip_runtime.h>
#include <hip/hip_bf16.h>

#define N_NODES 100000
#define N_EDGES 1600000
#define IN_F 256
#define OUT_F 128

typedef __attribute__((ext_vector_type(8))) __bf16 bf16x8;
typedef __attribute__((ext_vector_type(4))) float f32x4;

// ---------- helpers ----------
__device__ __forceinline__ float bf16_lo(unsigned int p) {
    union { unsigned int i; float f; } u; u.i = p << 16; return u.f;
}
__device__ __forceinline__ float bf16_hi(unsigned int p) {
    union { unsigned int i; float f; } u; u.i = p & 0xffff0000u; return u.f;
}
__device__ __forceinline__ unsigned short f2bf(float f) {
    union { float f; unsigned int i; } u; u.f = f;
    unsigned int r = u.i + 0x7fff + ((u.i >> 16) & 1);   // RNE (finite data only)
    return (unsigned short)(r >> 16);
}

// ---------- kernel 0: W fp32 [K][N] -> bf16 transposed wt [N][K] ----------
__global__ __launch_bounds__(256) void wconv_kernel(
    const float* __restrict__ weight, unsigned short* __restrict__ wt) {
  int id = blockIdx.x * 256 + threadIdx.x;   // 32768 = 256*128
  int col = id & 127;
  int k   = id >> 7;
  wt[(size_t)col * IN_F + k] = f2bf(weight[(size_t)k * OUT_F + col]);
}

// ---------- kernel 1: support = X @ W via MFMA, bf16 output ----------
// block = 256 thr (4 waves). Tile: 64 rows x 128 cols, K_STEP=64 (4 steps).
// LDS: Xt [64][72] ushort (9216 B) + Wt [128][72] ushort (18432 B) = 27648 B.
#define XS 72
#define WSS 72
__global__ __launch_bounds__(256) void gemm_xw_mfma(
    const float* __restrict__ x, const unsigned short* __restrict__ wt,
    unsigned int* __restrict__ support /* N_NODES x 64 uints (2 bf16 each) */) {
  __shared__ unsigned short smem[13824];
  unsigned short* Xt = smem;           // [64][XS]
  unsigned short* Wt = smem + 4608;    // [128][WSS]

  const int tid  = threadIdx.x;
  const int w    = tid >> 6;
  const int lane = tid & 63;
  const int l15  = lane & 15;
  const int lhi  = lane >> 4;
  const int row0 = blockIdx.x * 64;

  f32x4 acc[8];
  #pragma unroll
  for (int nt = 0; nt < 8; ++nt) acc[nt] = (f32x4){0.f, 0.f, 0.f, 0.f};

  for (int ks = 0; ks < 4; ++ks) {
    // stage X tile: 64 rows x 64 k fp32 -> bf16 LDS
    {
      int r = tid >> 2;
      int srow = row0 + r; if (srow >= N_NODES) srow = N_NODES - 1;
      const float* xp = x + (size_t)srow * IN_F + ks * 64;
      #pragma unroll
      for (int i = 0; i < 4; ++i) {
        int f4 = (tid & 3) + i * 4;          // 0..15
        float4 v = *(const float4*)(xp + f4 * 4);
        ushort4 h;
        h.x = f2bf(v.x); h.y = f2bf(v.y); h.z = f2bf(v.z); h.w = f2bf(v.w);
        *(ushort4*)(&Xt[r * XS + f4 * 4]) = h;
      }
    }
    // stage W tile: 128 cols x 64 k bf16 (already transposed in global)
    {
      int c = tid >> 1;
      const unsigned short* wp = wt + (size_t)c * IN_F + ks * 64;
      #pragma unroll
      for (int i = 0; i < 4; ++i) {
        int c8 = (tid & 1) * 4 + i;          // 0..7, 8 bf16 each
        uint4 v = *(const uint4*)(wp + c8 * 8);
        *(uint4*)(&Wt[c * WSS + c8 * 8]) = v;
      }
    }
    __syncthreads();
    #pragma unroll
    for (int kt = 0; kt < 2; ++kt) {
      bf16x8 a = *(const bf16x8*)(&Xt[(w * 16 + l15) * XS + kt * 32 + lhi * 8]);
      #pragma unroll
      for (int nt = 0; nt < 8; ++nt) {
        bf16x8 b = *(const bf16x8*)(&Wt[(nt * 16 + l15) * WSS + kt * 32 + lhi * 8]);
        acc[nt] = __builtin_amdgcn_mfma_f32_16x16x32_bf16(a, b, acc[nt], 0, 0, 0);
      }
    }
    __syncthreads();
  }

  // epilogue: acc -> LDS bf16 [64][128] -> coalesced global store
  unsigned short* Ot = smem;   // reuse (16384 B <= 27648 B)
  #pragma unroll
  for (int nt = 0; nt < 8; ++nt)
    #pragma unroll
    for (int r = 0; r < 4; ++r) {
      int orow = w * 16 + lhi * 4 + r;       // D row = (lane>>4)*4 + reg
      int ocol = nt * 16 + l15;              // D col = lane&15
      Ot[orow * 128 + ocol] = f2bf(acc[nt][r]);
    }
  __syncthreads();
  {
    int r = tid >> 2;
    int grow = row0 + r;
    if (grow < N_NODES) {
      const uint4* src = (const uint4*)(&Ot[r * 128]);
      uint4* dst = (uint4*)(support + (size_t)grow * 64);
      int c = tid & 3;
      #pragma unroll
      for (int i = 0; i < 4; ++i) dst[c + i * 4] = src[c + i * 4];
    }
  }
}

// ---------- kernel 2: row_ptr via binary search (edge_row is sorted) ----------
__global__ __launch_bounds__(256) void rowptr_kernel(
    const int* __restrict__ edge_row, int* __restrict__ row_ptr) {
  int r = blockIdx.x * 256 + threadIdx.x;
  if (r > N_NODES) return;
  int lo = 0, hi = N_EDGES;
  while (lo < hi) {
    int mid = (lo + hi) >> 1;
    if (edge_row[mid] < r) lo = mid + 1; else hi = mid;
  }
  row_ptr[r] = lo;  // first edge with row >= r
}

// ---------- kernel 3: CSR SpMM, one wave per output row, no atomics ----------
__global__ __launch_bounds__(256) void spmm_kernel(
    const unsigned int* __restrict__ support,  // 64 uints / row (2 bf16 each)
    const int* __restrict__ row_ptr,
    const int* __restrict__ edge_col,
    const float* __restrict__ edge_val,
    const float* __restrict__ bias,
    float* __restrict__ out) {
  int wid = (blockIdx.x * 256 + threadIdx.x) >> 6;   // row id
  if (wid >= N_NODES) return;
  int lane  = threadIdx.x & 63;
  int start = row_ptr[wid];
  int end   = row_ptr[wid + 1];
  float acc0 = 0.f, acc1 = 0.f;

  int e = start;
  for (; e + 4 <= end; e += 4) {
    int   c0 = edge_col[e + 0], c1 = edge_col[e + 1];
    int   c2 = edge_col[e + 2], c3 = edge_col[e + 3];
    float v0 = edge_val[e + 0], v1 = edge_val[e + 1];
    float v2 = edge_val[e + 2], v3 = edge_val[e + 3];
    unsigned int s0 = support[(size_t)c0 * 64 + lane];
    unsigned int s1 = support[(size_t)c1 * 64 + lane];
    unsigned int s2 = support[(size_t)c2 * 64 + lane];
    unsigned int s3 = support[(size_t)c3 * 64 + lane];
    acc0 += v0 * bf16_lo(s0); acc1 += v0 * bf16_hi(s0);
    acc0 += v1 * bf16_lo(s1); acc1 += v1 * bf16_hi(s1);
    acc0 += v2 * bf16_lo(s2); acc1 += v2 * bf16_hi(s2);
    acc0 += v3 * bf16_lo(s3); acc1 += v3 * bf16_hi(s3);
  }
  for (; e < end; ++e) {
    int   c = edge_col[e];
    float v = edge_val[e];
    unsigned int s = support[(size_t)c * 64 + lane];
    acc0 += v * bf16_lo(s); acc1 += v * bf16_hi(s);
  }
  float2 b = *(const float2*)(bias + lane * 2);
  float2 o; o.x = acc0 + b.x; o.y = acc1 + b.y;
  *(float2*)(out + (size_t)wid * OUT_F + lane * 2) = o;
}

// ---------- launch ----------
extern "C" void kernel_launch(void* const* d_in, const int* in_sizes, int n_in,
                              void* d_out, int out_size, void* d_ws, size_t ws_size,
                              hipStream_t stream) {
  const float* x        = (const float*)d_in[0];
  const int*   edge_row = (const int*)  d_in[1];
  const int*   edge_col = (const int*)  d_in[2];
  const float* edge_val = (const float*)d_in[3];
  const float* weight   = (const float*)d_in[4];
  const float* bias     = (const float*)d_in[5];
  float* out = (float*)d_out;

  unsigned char* ws = (unsigned char*)d_ws;
  size_t support_bytes = (size_t)N_NODES * OUT_F * 2;            // 25.6 MB bf16
  unsigned int* support = (unsigned int*)ws;
  size_t rp_off = (support_bytes + 255) & ~(size_t)255;
  int* row_ptr = (int*)(ws + rp_off);
  size_t wt_off = (rp_off + (size_t)(N_NODES + 1) * 4 + 255) & ~(size_t)255;
  unsigned short* wt = (unsigned short*)(ws + wt_off);

  hipLaunchKernelGGL(rowptr_kernel, dim3((N_NODES + 1 + 255) / 256), dim3(256), 0, stream,
                     edge_row, row_ptr);
  hipLaunchKernelGGL(wconv_kernel, dim3(128), dim3(256), 0, stream,
                     weight, wt);
  hipLaunchKernelGGL(gemm_xw_mfma, dim3((N_NODES + 63) / 64), dim3(256), 0, stream,
                     x, wt, support);
  hipLaunchKernelGGL(spmm_kernel, dim3(N_NODES / 4), dim3(256), 0, stream,
                     support, row_ptr, edge_col, edge_val, bias, out);
}